// Round 3
// baseline (600.667 us; speedup 1.0000x reference)
//
#include <hip/hip_runtime.h>
#include <hip/hip_bf16.h>
#include <math.h>

// ---------------------------------------------------------------------------
// SimpleMoEModel: dense GEMM -> top1-MoE -> top1-MoE -> residual -> mean ->
// log_softmax -> NLL.  B=8 S=2048 D=1024 E=8, capacity = T/E = 2048.
//
// Round 3:
//  - GEMMs: BK=64 K-step (half the barriers of BK=32), global_load_lds w=16,
//    XOR chunk swizzle p = g ^ (row&7) -> conflict-free ds_read_b128.
//  - Ballot-based routing scan (8 waves, one expert per wave).
//  - Vectorized reduce_sent, parallel loss (atomicAdd), fused memsets.
// ---------------------------------------------------------------------------

#define TOKS 16384
#define DIM 1024
#define NEXP 8
#define CAP 2048
#define BATCH 8
#define SEQ 2048

typedef __bf16 bf16_t;
typedef __bf16 bf16x8 __attribute__((ext_vector_type(8)));
typedef float fx4 __attribute__((ext_vector_type(4)));

__device__ __forceinline__ void gll16(const bf16_t* g, bf16_t* l) {
  __builtin_amdgcn_global_load_lds(
      (const __attribute__((address_space(1))) unsigned int*)g,
      (__attribute__((address_space(3))) unsigned int*)l, 16, 0, 0);
}

// ---------------- weight prep: Wt[m][n][k] = (bf16)Wsrc[m][k][n] -----------
__global__ __launch_bounds__(256) void k_prep_w(
    const float* __restrict__ W1, const float* __restrict__ We2,
    const float* __restrict__ We3, bf16_t* __restrict__ Wt) {
  __shared__ float t[64][65];
  const int m = blockIdx.z;
  const float* src = (m == 0) ? W1
                     : (m <= 8) ? We2 + (size_t)(m - 1) * DIM * DIM
                                : We3 + (size_t)(m - 9) * DIM * DIM;
  bf16_t* dst = Wt + (size_t)m * DIM * DIM;
  const int n0 = blockIdx.x * 64, k0 = blockIdx.y * 64;
  const int tid = threadIdx.x;
  const int r = tid >> 4, c4 = (tid & 15) * 4;
#pragma unroll
  for (int i = 0; i < 4; i++) {
    float4 v = *(const float4*)&src[(size_t)(k0 + i * 16 + r) * DIM + n0 + c4];
    t[i * 16 + r][c4] = v.x;
    t[i * 16 + r][c4 + 1] = v.y;
    t[i * 16 + r][c4 + 2] = v.z;
    t[i * 16 + r][c4 + 3] = v.w;
  }
  __syncthreads();
#pragma unroll
  for (int i = 0; i < 4; i++) {
    int rn = i * 16 + r;
    union { bf16_t b[4]; uint2 u; } tmp;
#pragma unroll
    for (int j = 0; j < 4; j++) tmp.b[j] = (bf16_t)t[c4 + j][rn];
    *(uint2*)&dst[(size_t)(n0 + rn) * DIM + k0 + c4] = tmp.u;
  }
}

// ---------------- x fp32 -> bf16 -------------------------------------------
__global__ __launch_bounds__(256) void k_cvt_x(const float* __restrict__ x,
                                               bf16_t* __restrict__ xb) {
  size_t i = ((size_t)blockIdx.x * 256 + threadIdx.x) * 8;
  float4 a = *(const float4*)&x[i];
  float4 b = *(const float4*)&x[i + 4];
  union { bf16_t h[8]; uint4 u; } t;
  t.h[0] = (bf16_t)a.x; t.h[1] = (bf16_t)a.y; t.h[2] = (bf16_t)a.z; t.h[3] = (bf16_t)a.w;
  t.h[4] = (bf16_t)b.x; t.h[5] = (bf16_t)b.y; t.h[6] = (bf16_t)b.z; t.h[7] = (bf16_t)b.w;
  *(uint4*)&xb[i] = t.u;
}

// ============ shared GEMM inner loop (BK=64), as a macro body ==============
// Staging mapping: thread tid, iter i (0..3): chunk c = tid + 256*i,
// row r = (tid>>3) + 32*i, LDS pos = tid&7, global chunk = (tid&7)^((tid>>3)&7).
// Fragment read: row R, k-chunk g = s*4+quad at LDS pos g^(l15&7).

// ---------------- dense GEMM: h = xb @ W1t + b1 ----------------------------
__global__ __launch_bounds__(256) void k_gemm_dense(
    const bf16_t* __restrict__ A, const bf16_t* __restrict__ Bt,
    const float* __restrict__ bias, bf16_t* __restrict__ out) {
  __shared__ alignas(16) bf16_t As[128 * 64];
  __shared__ alignas(16) bf16_t Bs[128 * 64];
  const int tid = threadIdx.x;
  const int lane = tid & 63, wave = tid >> 6;
  const int quad = lane >> 4, l15 = lane & 15;
  const int wr = (wave >> 1) * 64, wc = (wave & 1) * 64;
  const int n0 = blockIdx.x * 128, m0 = blockIdx.y * 128;
  const int kc = (tid & 7) ^ ((tid >> 3) & 7);  // swizzled global k-chunk
  const int rbase = tid >> 3;                   // row for i=0
  const int sw0 = ((0 * 4) ^ (l15 & 7)) << 3;   // s=0 base (quad xored below)

  const bf16_t* gA[4];
  const bf16_t* gB[4];
  bf16_t* lA[4];
  bf16_t* lB[4];
#pragma unroll
  for (int i = 0; i < 4; i++) {
    int r = rbase + 32 * i;
    gA[i] = A + (size_t)(m0 + r) * DIM + kc * 8;
    gB[i] = Bt + (size_t)(n0 + r) * DIM + kc * 8;
    lA[i] = &As[(wave * 64 + 256 * i) * 8];
    lB[i] = &Bs[(wave * 64 + 256 * i) * 8];
  }

  fx4 acc[4][4];
#pragma unroll
  for (int i = 0; i < 4; i++)
#pragma unroll
    for (int j = 0; j < 4; j++) acc[i][j] = (fx4)0.0f;

  for (int k0 = 0; k0 < DIM; k0 += 64) {
#pragma unroll
    for (int i = 0; i < 4; i++) gll16(gA[i] + k0, lA[i]);
#pragma unroll
    for (int i = 0; i < 4; i++) gll16(gB[i] + k0, lB[i]);
    __syncthreads();
#pragma unroll
    for (int s = 0; s < 2; s++) {
      const int pofs = ((s * 4 + quad) ^ (l15 & 7)) << 3;
      bf16x8 av[4], bv[4];
#pragma unroll
      for (int i = 0; i < 4; i++)
        av[i] = *(const bf16x8*)&As[(wr + i * 16 + l15) * 64 + pofs];
#pragma unroll
      for (int j = 0; j < 4; j++)
        bv[j] = *(const bf16x8*)&Bs[(wc + j * 16 + l15) * 64 + pofs];
#pragma unroll
      for (int i = 0; i < 4; i++)
#pragma unroll
        for (int j = 0; j < 4; j++)
          acc[i][j] = __builtin_amdgcn_mfma_f32_16x16x32_bf16(av[i], bv[j], acc[i][j], 0, 0, 0);
    }
    __syncthreads();
  }
  (void)sw0;
#pragma unroll
  for (int j = 0; j < 4; j++) {
    int col = n0 + wc + j * 16 + l15;
    float bb = bias[col];
#pragma unroll
    for (int i = 0; i < 4; i++)
#pragma unroll
      for (int r = 0; r < 4; r++) {
        int m = m0 + wr + i * 16 + quad * 4 + r;  // C/D layout (m89/m91)
        out[(size_t)m * DIM + col] = (bf16_t)(acc[i][j][r] + bb);
      }
  }
}

// ---------------- gating: logits=act@Wg, softmax prob of argmax ------------
__global__ __launch_bounds__(256) void k_gate(
    const bf16_t* __restrict__ act, const float* __restrict__ Wg,
    int* __restrict__ idx, float* __restrict__ gate) {
  const int t = blockIdx.x * 4 + (threadIdx.x >> 6);
  const int lane = threadIdx.x & 63;
  const bf16_t* a = act + (size_t)t * DIM + lane * 16;
  union { bf16_t b[8]; uint4 u; } x0, x1;
  x0.u = *(const uint4*)a;
  x1.u = *(const uint4*)(a + 8);
  float av[16];
#pragma unroll
  for (int j = 0; j < 8; j++) { av[j] = (float)x0.b[j]; av[8 + j] = (float)x1.b[j]; }
  float acc[8] = {0.f, 0.f, 0.f, 0.f, 0.f, 0.f, 0.f, 0.f};
  const float* wg = Wg + (size_t)lane * 16 * 8;
#pragma unroll
  for (int d = 0; d < 16; d++) {
    float4 w0 = *(const float4*)&wg[d * 8];
    float4 w1 = *(const float4*)&wg[d * 8 + 4];
    acc[0] += av[d] * w0.x; acc[1] += av[d] * w0.y;
    acc[2] += av[d] * w0.z; acc[3] += av[d] * w0.w;
    acc[4] += av[d] * w1.x; acc[5] += av[d] * w1.y;
    acc[6] += av[d] * w1.z; acc[7] += av[d] * w1.w;
  }
#pragma unroll
  for (int off = 32; off; off >>= 1)
#pragma unroll
    for (int e = 0; e < 8; e++) acc[e] += __shfl_xor(acc[e], off);
  if (lane == 0) {
    float best = acc[0];
    int bi = 0;
#pragma unroll
    for (int e = 1; e < 8; e++)
      if (acc[e] > best) { best = acc[e]; bi = e; }  // strict >: first max wins
    float s = 0.f;
#pragma unroll
    for (int e = 0; e < 8; e++) s += expf(acc[e] - best);
    idx[t] = bi;
    gate[t] = 1.0f / s;
  }
}

// ---------------- routing scan: wave e scans token stream for expert e -----
__global__ __launch_bounds__(512) void k_scan(
    const int* __restrict__ idx, int* __restrict__ tok, int* __restrict__ cnt) {
  const int w = threadIdx.x >> 6;   // expert this wave owns
  const int lane = threadIdx.x & 63;
  const unsigned long long ltmask = (1ull << lane) - 1ull;
  int base = 0;
  int e = idx[lane];
  for (int ch = 0; ch < 256; ch++) {
    int enxt = (ch < 255) ? idx[(ch + 1) * 64 + lane] : 0;
    bool m = (e == w);
    unsigned long long mask = __ballot(m);
    int pos = base + __popcll(mask & ltmask);
    if (m && pos < CAP) tok[w * CAP + pos] = ch * 64 + lane;
    base += __popcll(mask);
    e = enxt;
  }
  if (lane == 0) cnt[w] = base < CAP ? base : CAP;
}

// ---------------- expert GEMM with gathered A + combine epilogue -----------
__global__ __launch_bounds__(256) void k_gemm_expert(
    const bf16_t* __restrict__ Ain, const bf16_t* __restrict__ Wt,
    const float* __restrict__ be, const int* __restrict__ tok,
    const int* __restrict__ cnt, const float* __restrict__ gate,
    const bf16_t* __restrict__ zp, bf16_t* __restrict__ outp) {
  const int e = blockIdx.z;
  const int count = cnt[e];
  const int c0 = blockIdx.y * 128;
  if (c0 >= count) return;
  const int n0 = blockIdx.x * 128;
  const bf16_t* Bt = Wt + (size_t)e * DIM * DIM;
  const float* bias = be + (size_t)e * DIM;
  const int* tk = tok + e * CAP;

  __shared__ alignas(16) bf16_t As[128 * 64];
  __shared__ alignas(16) bf16_t Bs[128 * 64];
  const int tid = threadIdx.x;
  const int lane = tid & 63, wave = tid >> 6;
  const int quad = lane >> 4, l15 = lane & 15;
  const int wr = (wave >> 1) * 64, wc = (wave & 1) * 64;
  const int kc = (tid & 7) ^ ((tid >> 3) & 7);
  const int rbase = tid >> 3;

  const bf16_t* gA[4];
  const bf16_t* gB[4];
  bf16_t* lA[4];
  bf16_t* lB[4];
#pragma unroll
  for (int i = 0; i < 4; i++) {
    int r = rbase + 32 * i;
    int ca = c0 + r;
    gA[i] = (ca < count) ? Ain + (size_t)tk[ca] * DIM + kc * 8 : zp;
    gB[i] = Bt + (size_t)(n0 + r) * DIM + kc * 8;
    lA[i] = &As[(wave * 64 + 256 * i) * 8];
    lB[i] = &Bs[(wave * 64 + 256 * i) * 8];
  }

  fx4 acc[4][4];
#pragma unroll
  for (int i = 0; i < 4; i++)
#pragma unroll
    for (int j = 0; j < 4; j++) acc[i][j] = (fx4)0.0f;

  for (int k0 = 0; k0 < DIM; k0 += 64) {
#pragma unroll
    for (int i = 0; i < 4; i++) gll16(gA[i] + k0, lA[i]);
#pragma unroll
    for (int i = 0; i < 4; i++) gll16(gB[i] + k0, lB[i]);
    __syncthreads();
#pragma unroll
    for (int s = 0; s < 2; s++) {
      const int pofs = ((s * 4 + quad) ^ (l15 & 7)) << 3;
      bf16x8 av[4], bv[4];
#pragma unroll
      for (int i = 0; i < 4; i++)
        av[i] = *(const bf16x8*)&As[(wr + i * 16 + l15) * 64 + pofs];
#pragma unroll
      for (int j = 0; j < 4; j++)
        bv[j] = *(const bf16x8*)&Bs[(wc + j * 16 + l15) * 64 + pofs];
#pragma unroll
      for (int i = 0; i < 4; i++)
#pragma unroll
        for (int j = 0; j < 4; j++)
          acc[i][j] = __builtin_amdgcn_mfma_f32_16x16x32_bf16(av[i], bv[j], acc[i][j], 0, 0, 0);
    }
    __syncthreads();
  }
  // combine: out[t] = gate[t] * (acc + be[e]); dropped tokens stay memset-0
#pragma unroll
  for (int i = 0; i < 4; i++)
#pragma unroll
    for (int r = 0; r < 4; r++) {
      int c = c0 + wr + i * 16 + quad * 4 + r;
      if (c < count) {
        int t = tk[c];
        float g = gate[t];
#pragma unroll
        for (int j = 0; j < 4; j++) {
          int col = n0 + wc + j * 16 + l15;
          outp[(size_t)t * DIM + col] = (bf16_t)((acc[i][j][r] + bias[col]) * g);
        }
      }
    }
}

// ---------------- residual mean over S (vectorized, atomics) ---------------
__global__ __launch_bounds__(256) void k_reduce_sent(
    const bf16_t* __restrict__ h, const bf16_t* __restrict__ o2,
    float* __restrict__ sent) {
  const int tid = threadIdx.x;
  const int d8 = (tid & 127) * 8;
  const int sg = tid >> 7;  // 0/1
  const int b = blockIdx.y;
  const int s0 = blockIdx.x * 64 + sg * 32;
  float acc[8] = {0.f, 0.f, 0.f, 0.f, 0.f, 0.f, 0.f, 0.f};
  const size_t base = ((size_t)b * SEQ + s0) * DIM + d8;
  for (int i = 0; i < 32; i++) {
    union { bf16_t v[8]; uint4 u; } hh, oo;
    hh.u = *(const uint4*)&h[base + (size_t)i * DIM];
    oo.u = *(const uint4*)&o2[base + (size_t)i * DIM];
#pragma unroll
    for (int j = 0; j < 8; j++) acc[j] += (float)hh.v[j] + (float)oo.v[j];
  }
#pragma unroll
  for (int j = 0; j < 8; j++)
    atomicAdd(&sent[b * DIM + d8 + j], acc[j] * (1.0f / SEQ));
}

// ---------------- loss: one block per batch, atomicAdd into out ------------
__global__ __launch_bounds__(256) void k_loss(
    const float* __restrict__ sent, const int* __restrict__ y,
    float* __restrict__ out) {
  const int b = blockIdx.x, tid = threadIdx.x;
  const float* sb = sent + b * DIM;
  __shared__ float red[256];
  float m = -1e30f;
  for (int d = tid; d < DIM; d += 256) m = fmaxf(m, sb[d]);
  red[tid] = m;
  __syncthreads();
  for (int s = 128; s; s >>= 1) {
    if (tid < s) red[tid] = fmaxf(red[tid], red[tid + s]);
    __syncthreads();
  }
  m = red[0];
  __syncthreads();
  float sum = 0.f;
  for (int d = tid; d < DIM; d += 256) sum += expf(sb[d] - m);
  red[tid] = sum;
  __syncthreads();
  for (int s = 128; s; s >>= 1) {
    if (tid < s) red[tid] += red[tid + s];
    __syncthreads();
  }
  if (tid == 0) atomicAdd(out, (m + logf(red[0]) - sb[y[b]]) * (1.0f / BATCH));
}

// ---------------------------------------------------------------------------
extern "C" void kernel_launch(void* const* d_in, const int* in_sizes, int n_in,
                              void* d_out, int out_size, void* d_ws, size_t ws_size,
                              hipStream_t stream) {
  (void)in_sizes; (void)n_in; (void)out_size; (void)ws_size;
  const float* x   = (const float*)d_in[0];
  const int*   y   = (const int*)d_in[1];
  const float* W1  = (const float*)d_in[2];
  const float* b1  = (const float*)d_in[3];
  const float* Wg2 = (const float*)d_in[4];
  const float* We2 = (const float*)d_in[5];
  const float* be2 = (const float*)d_in[6];
  const float* Wg3 = (const float*)d_in[7];
  const float* We3 = (const float*)d_in[8];
  const float* be3 = (const float*)d_in[9];

  char* p = (char*)d_ws;
  size_t off = 0;
  auto carve = [&](size_t bytes) -> char* {
    char* r = p + off;
    off += (bytes + 255) & ~(size_t)255;
    return r;
  };
  bf16_t* Wt   = (bf16_t*)carve((size_t)17 * DIM * DIM * 2);  // 0:W1t 1..8:We2t 9..16:We3t
  bf16_t* h    = (bf16_t*)carve((size_t)TOKS * DIM * 2);
  // --- contiguous zero region: o1, sent, zp (single memset) ---
  size_t zoff0 = off;
  bf16_t* o1   = (bf16_t*)carve((size_t)TOKS * DIM * 2);
  float*  sent = (float*)carve(BATCH * DIM * 4);
  bf16_t* zp   = (bf16_t*)carve(4096);
  size_t zbytes = off - zoff0;
  // ------------------------------------------------------------
  bf16_t* o2   = (bf16_t*)carve((size_t)TOKS * DIM * 2);  // aliases xb lifetime
  int*    idx  = (int*)carve(TOKS * 4);
  float*  gate = (float*)carve(TOKS * 4);
  int*    tok  = (int*)carve(NEXP * CAP * 4);
  int*    cnt  = (int*)carve(NEXP * 4);
  bf16_t* xb   = o2;  // x-bf16 dead before o2 is born

  hipMemsetAsync(o1, 0, zbytes, stream);      // o1 + sent + zp
  hipMemsetAsync(d_out, 0, 4, stream);        // loss accumulates via atomics

  // prep: weight transpose+convert, x convert
  k_prep_w<<<dim3(16, 16, 17), 256, 0, stream>>>(W1, We2, We3, Wt);
  k_cvt_x<<<TOKS * DIM / 8 / 256, 256, 0, stream>>>(x, xb);

  // dense pre-layer
  k_gemm_dense<<<dim3(DIM / 128, TOKS / 128), 256, 0, stream>>>(xb, Wt, b1, h);
  hipMemsetAsync(o2, 0, (size_t)TOKS * DIM * 2, stream);  // xb dead; o2 born

  // MoE layer 2
  k_gate<<<TOKS / 4, 256, 0, stream>>>(h, Wg2, idx, gate);
  k_scan<<<1, 512, 0, stream>>>(idx, tok, cnt);
  k_gemm_expert<<<dim3(DIM / 128, CAP / 128, NEXP), 256, 0, stream>>>(
      h, Wt + (size_t)1 * DIM * DIM, be2, tok, cnt, gate, zp, o1);

  // MoE layer 3
  k_gate<<<TOKS / 4, 256, 0, stream>>>(o1, Wg3, idx, gate);
  k_scan<<<1, 512, 0, stream>>>(idx, tok, cnt);
  k_gemm_expert<<<dim3(DIM / 128, CAP / 128, NEXP), 256, 0, stream>>>(
      o1, Wt + (size_t)9 * DIM * DIM, be3, tok, cnt, gate, zp, o2);

  // residual + sentence mean + CE loss
  k_reduce_sent<<<dim3(SEQ / 64, BATCH), 256, 0, stream>>>(h, o2, sent);
  k_loss<<<BATCH, 256, 0, stream>>>(sent, y, (float*)d_out);
}

// Round 4
// 461.722 us; speedup vs baseline: 1.3009x; 1.3009x over previous
//
#include <hip/hip_runtime.h>
#include <hip/hip_bf16.h>
#include <math.h>

// ---------------------------------------------------------------------------
// SimpleMoEModel: dense GEMM -> top1-MoE -> top1-MoE -> residual -> mean ->
// log_softmax -> NLL.  B=8 S=2048 D=1024 E=8, capacity = T/E = 2048.
//
// Round 4:
//  - Gating as MFMA GEMM [T,1024]x[1024,16] (8 experts padded; cols 8..15 are
//    ignored duplicates), argmax+softmax fused into the epilogue. Replaces
//    the 64 us uncoalesced GEMV (lane-strided Wg reads = 64-way replay).
//  - k_route: 8 expert-blocks x 1024 thr, shfl-scan (kills the serial
//    256-iter ballot chain). Emits drop list; k_zero_rows zeroes only
//    dropped rows (replaces 2x 32MB memsets).
//  - GEMMs: BK=64, global_load_lds w=16, XOR chunk swizzle (0 conflicts, r2).
// ---------------------------------------------------------------------------

#define TOKS 16384
#define DIM 1024
#define NEXP 8
#define CAP 2048
#define BATCH 8
#define SEQ 2048

typedef __bf16 bf16_t;
typedef __bf16 bf16x8 __attribute__((ext_vector_type(8)));
typedef float fx4 __attribute__((ext_vector_type(4)));

__device__ __forceinline__ void gll16(const bf16_t* g, bf16_t* l) {
  __builtin_amdgcn_global_load_lds(
      (const __attribute__((address_space(1))) unsigned int*)g,
      (__attribute__((address_space(3))) unsigned int*)l, 16, 0, 0);
}

// ---------------- weight prep: Wt[m][n][k] = (bf16)Wsrc[m][k][n] -----------
__global__ __launch_bounds__(256) void k_prep_w(
    const float* __restrict__ W1, const float* __restrict__ We2,
    const float* __restrict__ We3, bf16_t* __restrict__ Wt) {
  __shared__ float t[64][65];
  const int m = blockIdx.z;
  const float* src = (m == 0) ? W1
                     : (m <= 8) ? We2 + (size_t)(m - 1) * DIM * DIM
                                : We3 + (size_t)(m - 9) * DIM * DIM;
  bf16_t* dst = Wt + (size_t)m * DIM * DIM;
  const int n0 = blockIdx.x * 64, k0 = blockIdx.y * 64;
  const int tid = threadIdx.x;
  const int r = tid >> 4, c4 = (tid & 15) * 4;
#pragma unroll
  for (int i = 0; i < 4; i++) {
    float4 v = *(const float4*)&src[(size_t)(k0 + i * 16 + r) * DIM + n0 + c4];
    t[i * 16 + r][c4] = v.x;
    t[i * 16 + r][c4 + 1] = v.y;
    t[i * 16 + r][c4 + 2] = v.z;
    t[i * 16 + r][c4 + 3] = v.w;
  }
  __syncthreads();
#pragma unroll
  for (int i = 0; i < 4; i++) {
    int rn = i * 16 + r;
    union { bf16_t b[4]; uint2 u; } tmp;
#pragma unroll
    for (int j = 0; j < 4; j++) tmp.b[j] = (bf16_t)t[c4 + j][rn];
    *(uint2*)&dst[(size_t)(n0 + rn) * DIM + k0 + c4] = tmp.u;
  }
}

// ---------------- Wg prep: WgP[which][d>>3][e][d&7] = (bf16)Wg[d][e] -------
__global__ __launch_bounds__(256) void k_prep_wg(
    const float* __restrict__ Wg2, const float* __restrict__ Wg3,
    bf16_t* __restrict__ WgP) {
  const int which = blockIdx.x;
  const float* src = which ? Wg3 : Wg2;
  bf16_t* dst = WgP + which * (128 * 8 * 8);
  const int tid = threadIdx.x;
#pragma unroll
  for (int j = 0; j < 4; j++) {
    int d = tid * 4 + j;
    float4 a = *(const float4*)&src[d * 8];
    float4 b = *(const float4*)&src[d * 8 + 4];
    float v[8] = {a.x, a.y, a.z, a.w, b.x, b.y, b.z, b.w};
#pragma unroll
    for (int e = 0; e < 8; e++)
      dst[((d >> 3) * 8 + e) * 8 + (d & 7)] = (bf16_t)v[e];
  }
}

// ---------------- x fp32 -> bf16 -------------------------------------------
__global__ __launch_bounds__(256) void k_cvt_x(const float* __restrict__ x,
                                               bf16_t* __restrict__ xb) {
  size_t i = ((size_t)blockIdx.x * 256 + threadIdx.x) * 8;
  float4 a = *(const float4*)&x[i];
  float4 b = *(const float4*)&x[i + 4];
  union { bf16_t h[8]; uint4 u; } t;
  t.h[0] = (bf16_t)a.x; t.h[1] = (bf16_t)a.y; t.h[2] = (bf16_t)a.z; t.h[3] = (bf16_t)a.w;
  t.h[4] = (bf16_t)b.x; t.h[5] = (bf16_t)b.y; t.h[6] = (bf16_t)b.z; t.h[7] = (bf16_t)b.w;
  *(uint4*)&xb[i] = t.u;
}

// ---------------- dense GEMM: h = xb @ W1t + b1 (BK=64) --------------------
__global__ __launch_bounds__(256) void k_gemm_dense(
    const bf16_t* __restrict__ A, const bf16_t* __restrict__ Bt,
    const float* __restrict__ bias, bf16_t* __restrict__ out) {
  __shared__ alignas(16) bf16_t As[128 * 64];
  __shared__ alignas(16) bf16_t Bs[128 * 64];
  const int tid = threadIdx.x;
  const int lane = tid & 63, wave = tid >> 6;
  const int quad = lane >> 4, l15 = lane & 15;
  const int wr = (wave >> 1) * 64, wc = (wave & 1) * 64;
  const int n0 = blockIdx.x * 128, m0 = blockIdx.y * 128;
  const int kc = (tid & 7) ^ ((tid >> 3) & 7);  // swizzled global k-chunk
  const int rbase = tid >> 3;

  const bf16_t* gA[4];
  const bf16_t* gB[4];
  bf16_t* lA[4];
  bf16_t* lB[4];
#pragma unroll
  for (int i = 0; i < 4; i++) {
    int r = rbase + 32 * i;
    gA[i] = A + (size_t)(m0 + r) * DIM + kc * 8;
    gB[i] = Bt + (size_t)(n0 + r) * DIM + kc * 8;
    lA[i] = &As[(wave * 64 + 256 * i) * 8];
    lB[i] = &Bs[(wave * 64 + 256 * i) * 8];
  }

  fx4 acc[4][4];
#pragma unroll
  for (int i = 0; i < 4; i++)
#pragma unroll
    for (int j = 0; j < 4; j++) acc[i][j] = (fx4)0.0f;

  for (int k0 = 0; k0 < DIM; k0 += 64) {
#pragma unroll
    for (int i = 0; i < 4; i++) gll16(gA[i] + k0, lA[i]);
#pragma unroll
    for (int i = 0; i < 4; i++) gll16(gB[i] + k0, lB[i]);
    __syncthreads();
#pragma unroll
    for (int s = 0; s < 2; s++) {
      const int pofs = ((s * 4 + quad) ^ (l15 & 7)) << 3;
      bf16x8 av[4], bv[4];
#pragma unroll
      for (int i = 0; i < 4; i++)
        av[i] = *(const bf16x8*)&As[(wr + i * 16 + l15) * 64 + pofs];
#pragma unroll
      for (int j = 0; j < 4; j++)
        bv[j] = *(const bf16x8*)&Bs[(wc + j * 16 + l15) * 64 + pofs];
#pragma unroll
      for (int i = 0; i < 4; i++)
#pragma unroll
        for (int j = 0; j < 4; j++)
          acc[i][j] = __builtin_amdgcn_mfma_f32_16x16x32_bf16(av[i], bv[j], acc[i][j], 0, 0, 0);
    }
    __syncthreads();
  }
#pragma unroll
  for (int j = 0; j < 4; j++) {
    int col = n0 + wc + j * 16 + l15;
    float bb = bias[col];
#pragma unroll
    for (int i = 0; i < 4; i++)
#pragma unroll
      for (int r = 0; r < 4; r++) {
        int m = m0 + wr + i * 16 + quad * 4 + r;  // C/D layout (m89/m91)
        out[(size_t)m * DIM + col] = (bf16_t)(acc[i][j][r] + bb);
      }
  }
}

// ---------------- MFMA gating: logits -> argmax+softmax inline -------------
// act [T,1024] bf16; WgP [128][8][8] bf16 (B-frag layout). M=64 per block.
__global__ __launch_bounds__(256) void k_gate_mm(
    const bf16_t* __restrict__ act, const bf16_t* __restrict__ WgP,
    int* __restrict__ idx, float* __restrict__ gate) {
  __shared__ alignas(16) bf16_t As[64 * 64];    // 8 KB
  __shared__ alignas(16) bf16_t WgS[128 * 64];  // 16 KB  [kc][8][8]
  __shared__ float L[64][8];
  const int tid = threadIdx.x;
  const int lane = tid & 63, wave = tid >> 6;
  const int quad = lane >> 4, l15 = lane & 15;
  const int m0 = blockIdx.x * 64;
  const int kc = (tid & 7) ^ ((tid >> 3) & 7);
  const int rbase = tid >> 3;  // 0..31

  // stage WgS once (identity copy, 1024 uint4)
#pragma unroll
  for (int j = 0; j < 4; j++)
    gll16(WgP + (j * 256 + wave * 64) * 8, &WgS[(j * 256 + wave * 64) * 8]);

  const bf16_t* gA[2];
  bf16_t* lA[2];
#pragma unroll
  for (int i = 0; i < 2; i++) {
    gA[i] = act + (size_t)(m0 + rbase + 32 * i) * DIM + kc * 8;
    lA[i] = &As[wave * 512 + i * 2048];
  }

  fx4 acc = (fx4)0.0f;
  for (int k0 = 0; k0 < DIM; k0 += 64) {
#pragma unroll
    for (int i = 0; i < 2; i++) gll16(gA[i] + k0, lA[i]);
    __syncthreads();
#pragma unroll
    for (int s = 0; s < 2; s++) {
      const int pofs = ((s * 4 + quad) ^ (l15 & 7)) << 3;
      bf16x8 av = *(const bf16x8*)&As[(wave * 16 + l15) * 64 + pofs];
      // B-frag: cols 8..15 duplicate 0..7 (ignored)
      bf16x8 bv = *(const bf16x8*)&WgS[((k0 >> 3) + s * 4 + quad) * 64 + (l15 & 7) * 8];
      acc = __builtin_amdgcn_mfma_f32_16x16x32_bf16(av, bv, acc, 0, 0, 0);
    }
    __syncthreads();
  }
  if (l15 < 8) {
#pragma unroll
    for (int r = 0; r < 4; r++) L[wave * 16 + quad * 4 + r][l15] = acc[r];
  }
  __syncthreads();
  if (tid < 64) {
    float lg[8];
#pragma unroll
    for (int e = 0; e < 8; e++) lg[e] = L[tid][e];
    float best = lg[0];
    int bi = 0;
#pragma unroll
    for (int e = 1; e < 8; e++)
      if (lg[e] > best) { best = lg[e]; bi = e; }  // strict >: first max wins
    float s = 0.f;
#pragma unroll
    for (int e = 0; e < 8; e++) s += expf(lg[e] - best);
    idx[m0 + tid] = bi;
    gate[m0 + tid] = 1.0f / s;
  }
}

// ---------------- routing: block e builds tok list for expert e ------------
__global__ __launch_bounds__(1024) void k_route(
    const int* __restrict__ idx, int* __restrict__ tok, int* __restrict__ cnt,
    int* __restrict__ drop, int* __restrict__ ndrop) {
  const int e = blockIdx.x;
  const int tid = threadIdx.x, lane = tid & 63, wv = tid >> 6;
  __shared__ int wsum[16];
  const int4* p = (const int4*)(idx + tid * 16);
  int m[16];
  int c = 0;
#pragma unroll
  for (int j = 0; j < 4; j++) {
    int4 v = p[j];
    m[j * 4 + 0] = (v.x == e);
    m[j * 4 + 1] = (v.y == e);
    m[j * 4 + 2] = (v.z == e);
    m[j * 4 + 3] = (v.w == e);
    c += m[j * 4] + m[j * 4 + 1] + m[j * 4 + 2] + m[j * 4 + 3];
  }
  int sc = c;  // intra-wave inclusive scan
#pragma unroll
  for (int off = 1; off < 64; off <<= 1) {
    int n = __shfl_up(sc, off);
    if (lane >= off) sc += n;
  }
  if (lane == 63) wsum[wv] = sc;
  __syncthreads();
  int wb = 0, tot = 0;
#pragma unroll
  for (int i = 0; i < 16; i++) {
    int s = wsum[i];
    tot += s;
    if (i < wv) wb += s;
  }
  int pos = wb + sc - c;  // exclusive prefix for this thread
#pragma unroll
  for (int j = 0; j < 16; j++) {
    if (m[j]) {
      if (pos < CAP) {
        tok[e * CAP + pos] = tid * 16 + j;
      } else {
        int di = atomicAdd(ndrop, 1);
        drop[di] = tid * 16 + j;
      }
      pos++;
    }
  }
  if (tid == 0) cnt[e] = tot < CAP ? tot : CAP;
}

// ---------------- zero rows of dropped tokens ------------------------------
__global__ __launch_bounds__(128) void k_zero_rows(
    bf16_t* __restrict__ buf, const int* __restrict__ drop,
    const int* __restrict__ ndrop) {
  const int nd = *ndrop;
  const uint4 z = {0u, 0u, 0u, 0u};
  for (int j = blockIdx.x; j < nd; j += gridDim.x) {
    int t = drop[j];
    ((uint4*)(buf + (size_t)t * DIM))[threadIdx.x] = z;
  }
}

// ---------------- expert GEMM with gathered A + combine epilogue -----------
__global__ __launch_bounds__(256) void k_gemm_expert(
    const bf16_t* __restrict__ Ain, const bf16_t* __restrict__ Wt,
    const float* __restrict__ be, const int* __restrict__ tok,
    const int* __restrict__ cnt, const float* __restrict__ gate,
    const bf16_t* __restrict__ zp, bf16_t* __restrict__ outp) {
  const int e = blockIdx.z;
  const int count = cnt[e];
  const int c0 = blockIdx.y * 128;
  if (c0 >= count) return;
  const int n0 = blockIdx.x * 128;
  const bf16_t* Bt = Wt + (size_t)e * DIM * DIM;
  const float* bias = be + (size_t)e * DIM;
  const int* tk = tok + e * CAP;

  __shared__ alignas(16) bf16_t As[128 * 64];
  __shared__ alignas(16) bf16_t Bs[128 * 64];
  const int tid = threadIdx.x;
  const int lane = tid & 63, wave = tid >> 6;
  const int quad = lane >> 4, l15 = lane & 15;
  const int wr = (wave >> 1) * 64, wc = (wave & 1) * 64;
  const int kc = (tid & 7) ^ ((tid >> 3) & 7);
  const int rbase = tid >> 3;

  const bf16_t* gA[4];
  const bf16_t* gB[4];
  bf16_t* lA[4];
  bf16_t* lB[4];
#pragma unroll
  for (int i = 0; i < 4; i++) {
    int r = rbase + 32 * i;
    int ca = c0 + r;
    gA[i] = (ca < count) ? Ain + (size_t)tk[ca] * DIM + kc * 8 : zp;
    gB[i] = Bt + (size_t)(n0 + r) * DIM + kc * 8;
    lA[i] = &As[(wave * 64 + 256 * i) * 8];
    lB[i] = &Bs[(wave * 64 + 256 * i) * 8];
  }

  fx4 acc[4][4];
#pragma unroll
  for (int i = 0; i < 4; i++)
#pragma unroll
    for (int j = 0; j < 4; j++) acc[i][j] = (fx4)0.0f;

  for (int k0 = 0; k0 < DIM; k0 += 64) {
#pragma unroll
    for (int i = 0; i < 4; i++) gll16(gA[i] + k0, lA[i]);
#pragma unroll
    for (int i = 0; i < 4; i++) gll16(gB[i] + k0, lB[i]);
    __syncthreads();
#pragma unroll
    for (int s = 0; s < 2; s++) {
      const int pofs = ((s * 4 + quad) ^ (l15 & 7)) << 3;
      bf16x8 av[4], bv[4];
#pragma unroll
      for (int i = 0; i < 4; i++)
        av[i] = *(const bf16x8*)&As[(wr + i * 16 + l15) * 64 + pofs];
#pragma unroll
      for (int j = 0; j < 4; j++)
        bv[j] = *(const bf16x8*)&Bs[(wc + j * 16 + l15) * 64 + pofs];
#pragma unroll
      for (int i = 0; i < 4; i++)
#pragma unroll
        for (int j = 0; j < 4; j++)
          acc[i][j] = __builtin_amdgcn_mfma_f32_16x16x32_bf16(av[i], bv[j], acc[i][j], 0, 0, 0);
    }
    __syncthreads();
  }
  // combine: out[t] = gate[t] * (acc + be[e]); dropped rows zeroed separately
#pragma unroll
  for (int i = 0; i < 4; i++)
#pragma unroll
    for (int r = 0; r < 4; r++) {
      int c = c0 + wr + i * 16 + quad * 4 + r;
      if (c < count) {
        int t = tk[c];
        float g = gate[t];
#pragma unroll
        for (int j = 0; j < 4; j++) {
          int col = n0 + wc + j * 16 + l15;
          outp[(size_t)t * DIM + col] = (bf16_t)((acc[i][j][r] + bias[col]) * g);
        }
      }
    }
}

// ---------------- residual mean over S (vectorized, atomics) ---------------
__global__ __launch_bounds__(256) void k_reduce_sent(
    const bf16_t* __restrict__ h, const bf16_t* __restrict__ o2,
    float* __restrict__ sent) {
  const int tid = threadIdx.x;
  const int d8 = (tid & 127) * 8;
  const int sg = tid >> 7;  // 0/1
  const int b = blockIdx.y;
  const int s0 = blockIdx.x * 64 + sg * 32;
  float acc[8] = {0.f, 0.f, 0.f, 0.f, 0.f, 0.f, 0.f, 0.f};
  const size_t base = ((size_t)b * SEQ + s0) * DIM + d8;
  for (int i = 0; i < 32; i++) {
    union { bf16_t v[8]; uint4 u; } hh, oo;
    hh.u = *(const uint4*)&h[base + (size_t)i * DIM];
    oo.u = *(const uint4*)&o2[base + (size_t)i * DIM];
#pragma unroll
    for (int j = 0; j < 8; j++) acc[j] += (float)hh.v[j] + (float)oo.v[j];
  }
#pragma unroll
  for (int j = 0; j < 8; j++)
    atomicAdd(&sent[b * DIM + d8 + j], acc[j] * (1.0f / SEQ));
}

// ---------------- loss: one block per batch, atomicAdd into out ------------
__global__ __launch_bounds__(256) void k_loss(
    const float* __restrict__ sent, const int* __restrict__ y,
    float* __restrict__ out) {
  const int b = blockIdx.x, tid = threadIdx.x;
  const float* sb = sent + b * DIM;
  __shared__ float red[256];
  float m = -1e30f;
  for (int d = tid; d < DIM; d += 256) m = fmaxf(m, sb[d]);
  red[tid] = m;
  __syncthreads();
  for (int s = 128; s; s >>= 1) {
    if (tid < s) red[tid] = fmaxf(red[tid], red[tid + s]);
    __syncthreads();
  }
  m = red[0];
  __syncthreads();
  float sum = 0.f;
  for (int d = tid; d < DIM; d += 256) sum += expf(sb[d] - m);
  red[tid] = sum;
  __syncthreads();
  for (int s = 128; s; s >>= 1) {
    if (tid < s) red[tid] += red[tid + s];
    __syncthreads();
  }
  if (tid == 0) atomicAdd(out, (m + logf(red[0]) - sb[y[b]]) * (1.0f / BATCH));
}

// ---------------------------------------------------------------------------
extern "C" void kernel_launch(void* const* d_in, const int* in_sizes, int n_in,
                              void* d_out, int out_size, void* d_ws, size_t ws_size,
                              hipStream_t stream) {
  (void)in_sizes; (void)n_in; (void)out_size; (void)ws_size;
  const float* x   = (const float*)d_in[0];
  const int*   y   = (const int*)d_in[1];
  const float* W1  = (const float*)d_in[2];
  const float* b1  = (const float*)d_in[3];
  const float* Wg2 = (const float*)d_in[4];
  const float* We2 = (const float*)d_in[5];
  const float* be2 = (const float*)d_in[6];
  const float* Wg3 = (const float*)d_in[7];
  const float* We3 = (const float*)d_in[8];
  const float* be3 = (const float*)d_in[9];

  char* p = (char*)d_ws;
  size_t off = 0;
  auto carve = [&](size_t bytes) -> char* {
    char* r = p + off;
    off += (bytes + 255) & ~(size_t)255;
    return r;
  };
  bf16_t* Wt   = (bf16_t*)carve((size_t)17 * DIM * DIM * 2);  // 0:W1t 1..8:We2t 9..16:We3t
  bf16_t* WgP  = (bf16_t*)carve(2 * 128 * 8 * 8 * 2);         // gate B-frag packs
  bf16_t* h    = (bf16_t*)carve((size_t)TOKS * DIM * 2);
  bf16_t* o1   = (bf16_t*)carve((size_t)TOKS * DIM * 2);
  bf16_t* o2   = (bf16_t*)carve((size_t)TOKS * DIM * 2);  // aliases xb lifetime
  int*    idx  = (int*)carve(TOKS * 4);
  float*  gate = (float*)carve(TOKS * 4);
  int*    tok  = (int*)carve(NEXP * CAP * 4);
  int*    cnt  = (int*)carve(NEXP * 4);
  int*    drop2 = (int*)carve(TOKS * 4);
  int*    drop3 = (int*)carve(TOKS * 4);
  // --- contiguous zero region: sent, zp, ndrop2, ndrop3 (single memset) ---
  size_t zoff0 = off;
  float*  sent = (float*)carve(BATCH * DIM * 4);
  bf16_t* zp   = (bf16_t*)carve(4096);
  int*    nd2  = (int*)carve(256);
  int*    nd3  = (int*)carve(256);
  size_t zbytes = off - zoff0;
  bf16_t* xb   = o2;  // x-bf16 dead before o2 is born

  hipMemsetAsync(sent, 0, zbytes, stream);  // sent + zp + nd2 + nd3
  hipMemsetAsync(d_out, 0, 4, stream);      // loss accumulates via atomics

  // prep: weight transpose+convert, gate weight pack, x convert
  k_prep_w<<<dim3(16, 16, 17), 256, 0, stream>>>(W1, We2, We3, Wt);
  k_prep_wg<<<2, 256, 0, stream>>>(Wg2, Wg3, WgP);
  k_cvt_x<<<TOKS * DIM / 8 / 256, 256, 0, stream>>>(x, xb);

  // dense pre-layer
  k_gemm_dense<<<dim3(DIM / 128, TOKS / 128), 256, 0, stream>>>(xb, Wt, b1, h);

  // MoE layer 2
  k_gate_mm<<<TOKS / 64, 256, 0, stream>>>(h, WgP, idx, gate);
  k_route<<<NEXP, 1024, 0, stream>>>(idx, tok, cnt, drop2, nd2);
  k_zero_rows<<<64, 128, 0, stream>>>(o1, drop2, nd2);
  k_gemm_expert<<<dim3(DIM / 128, CAP / 128, NEXP), 256, 0, stream>>>(
      h, Wt + (size_t)1 * DIM * DIM, be2, tok, cnt, gate, zp, o1);

  // MoE layer 3
  k_gate_mm<<<TOKS / 64, 256, 0, stream>>>(o1, WgP + 128 * 8 * 8, idx, gate);
  k_route<<<NEXP, 1024, 0, stream>>>(idx, tok, cnt, drop3, nd3);
  k_zero_rows<<<64, 128, 0, stream>>>(o2, drop3, nd3);
  k_gemm_expert<<<dim3(DIM / 128, CAP / 128, NEXP), 256, 0, stream>>>(
      o1, Wt + (size_t)9 * DIM * DIM, be3, tok, cnt, gate, zp, o2);

  // residual + sentence mean + CE loss
  k_reduce_sent<<<dim3(SEQ / 64, BATCH), 256, 0, stream>>>(h, o2, sent);
  k_loss<<<BATCH, 256, 0, stream>>>(sent, y, (float*)d_out);
}

// Round 5
// 398.866 us; speedup vs baseline: 1.5059x; 1.1576x over previous
//
#include <hip/hip_runtime.h>
#include <hip/hip_bf16.h>
#include <math.h>

// ---------------------------------------------------------------------------
// SimpleMoEModel: dense GEMM -> top1-MoE -> top1-MoE -> residual -> mean ->
// log_softmax -> NLL.  B=8 S=2048 D=1024 E=8, capacity = T/E = 2048.
//
// Round 5:
//  - FIX: k_gate_mm WgS staging used a wave-uniform global address with
//    global_load_lds (per-lane addr required, m104/m108) -> all expert
//    columns identical -> all tokens routed to expert 0 (the 28 MB
//    k_zero_rows write = exactly TOKS-CAP rows was the tell). Now +lane*8.
//  - XCD-aware 1D grids: dense GEMM: id&7 = XCD owns a 16-m-block slice,
//    8 n-blocks of one m-tile run back-to-back on one XCD (A fetched once,
//    B L2-resident). Expert GEMM: id&7 = expert -> weights L2-resident.
//  - GEMMs: BK=64, global_load_lds w=16, XOR chunk swizzle (0 conflicts).
// ---------------------------------------------------------------------------

#define TOKS 16384
#define DIM 1024
#define NEXP 8
#define CAP 2048
#define BATCH 8
#define SEQ 2048

typedef __bf16 bf16_t;
typedef __bf16 bf16x8 __attribute__((ext_vector_type(8)));
typedef float fx4 __attribute__((ext_vector_type(4)));

__device__ __forceinline__ void gll16(const bf16_t* g, bf16_t* l) {
  __builtin_amdgcn_global_load_lds(
      (const __attribute__((address_space(1))) unsigned int*)g,
      (__attribute__((address_space(3))) unsigned int*)l, 16, 0, 0);
}

// ---------------- weight prep: Wt[m][n][k] = (bf16)Wsrc[m][k][n] -----------
__global__ __launch_bounds__(256) void k_prep_w(
    const float* __restrict__ W1, const float* __restrict__ We2,
    const float* __restrict__ We3, bf16_t* __restrict__ Wt) {
  __shared__ float t[64][65];
  const int m = blockIdx.z;
  const float* src = (m == 0) ? W1
                     : (m <= 8) ? We2 + (size_t)(m - 1) * DIM * DIM
                                : We3 + (size_t)(m - 9) * DIM * DIM;
  bf16_t* dst = Wt + (size_t)m * DIM * DIM;
  const int n0 = blockIdx.x * 64, k0 = blockIdx.y * 64;
  const int tid = threadIdx.x;
  const int r = tid >> 4, c4 = (tid & 15) * 4;
#pragma unroll
  for (int i = 0; i < 4; i++) {
    float4 v = *(const float4*)&src[(size_t)(k0 + i * 16 + r) * DIM + n0 + c4];
    t[i * 16 + r][c4] = v.x;
    t[i * 16 + r][c4 + 1] = v.y;
    t[i * 16 + r][c4 + 2] = v.z;
    t[i * 16 + r][c4 + 3] = v.w;
  }
  __syncthreads();
#pragma unroll
  for (int i = 0; i < 4; i++) {
    int rn = i * 16 + r;
    union { bf16_t b[4]; uint2 u; } tmp;
#pragma unroll
    for (int j = 0; j < 4; j++) tmp.b[j] = (bf16_t)t[c4 + j][rn];
    *(uint2*)&dst[(size_t)(n0 + rn) * DIM + k0 + c4] = tmp.u;
  }
}

// ---------------- Wg prep: WgP[which][d>>3][e][d&7] = (bf16)Wg[d][e] -------
__global__ __launch_bounds__(256) void k_prep_wg(
    const float* __restrict__ Wg2, const float* __restrict__ Wg3,
    bf16_t* __restrict__ WgP) {
  const int which = blockIdx.x;
  const float* src = which ? Wg3 : Wg2;
  bf16_t* dst = WgP + which * (128 * 8 * 8);
  const int tid = threadIdx.x;
#pragma unroll
  for (int j = 0; j < 4; j++) {
    int d = tid * 4 + j;
    float4 a = *(const float4*)&src[d * 8];
    float4 b = *(const float4*)&src[d * 8 + 4];
    float v[8] = {a.x, a.y, a.z, a.w, b.x, b.y, b.z, b.w};
#pragma unroll
    for (int e = 0; e < 8; e++)
      dst[((d >> 3) * 8 + e) * 8 + (d & 7)] = (bf16_t)v[e];
  }
}

// ---------------- x fp32 -> bf16 -------------------------------------------
__global__ __launch_bounds__(256) void k_cvt_x(const float* __restrict__ x,
                                               bf16_t* __restrict__ xb) {
  size_t i = ((size_t)blockIdx.x * 256 + threadIdx.x) * 8;
  float4 a = *(const float4*)&x[i];
  float4 b = *(const float4*)&x[i + 4];
  union { bf16_t h[8]; uint4 u; } t;
  t.h[0] = (bf16_t)a.x; t.h[1] = (bf16_t)a.y; t.h[2] = (bf16_t)a.z; t.h[3] = (bf16_t)a.w;
  t.h[4] = (bf16_t)b.x; t.h[5] = (bf16_t)b.y; t.h[6] = (bf16_t)b.z; t.h[7] = (bf16_t)b.w;
  *(uint4*)&xb[i] = t.u;
}

// ---------------- dense GEMM: h = xb @ W1t + b1 (BK=64, XCD-swizzled) ------
__global__ __launch_bounds__(256) void k_gemm_dense(
    const bf16_t* __restrict__ A, const bf16_t* __restrict__ Bt,
    const float* __restrict__ bias, bf16_t* __restrict__ out) {
  __shared__ alignas(16) bf16_t As[128 * 64];
  __shared__ alignas(16) bf16_t Bs[128 * 64];
  const int tid = threadIdx.x;
  const int lane = tid & 63, wave = tid >> 6;
  const int quad = lane >> 4, l15 = lane & 15;
  const int wr = (wave >> 1) * 64, wc = (wave & 1) * 64;
  // XCD-aware decode: id&7 = XCD slot; XCD k owns m-blocks 16k..16k+15;
  // within an XCD, 8 n-blocks of one m-tile are consecutive (A fetched once).
  const int id = blockIdx.x;
  const int j_ = id >> 3;
  const int m0 = ((id & 7) * 16 + (j_ >> 3)) * 128;
  const int n0 = (j_ & 7) * 128;
  const int kc = (tid & 7) ^ ((tid >> 3) & 7);  // swizzled global k-chunk
  const int rbase = tid >> 3;

  const bf16_t* gA[4];
  const bf16_t* gB[4];
  bf16_t* lA[4];
  bf16_t* lB[4];
#pragma unroll
  for (int i = 0; i < 4; i++) {
    int r = rbase + 32 * i;
    gA[i] = A + (size_t)(m0 + r) * DIM + kc * 8;
    gB[i] = Bt + (size_t)(n0 + r) * DIM + kc * 8;
    lA[i] = &As[(wave * 64 + 256 * i) * 8];
    lB[i] = &Bs[(wave * 64 + 256 * i) * 8];
  }

  fx4 acc[4][4];
#pragma unroll
  for (int i = 0; i < 4; i++)
#pragma unroll
    for (int j = 0; j < 4; j++) acc[i][j] = (fx4)0.0f;

  for (int k0 = 0; k0 < DIM; k0 += 64) {
#pragma unroll
    for (int i = 0; i < 4; i++) gll16(gA[i] + k0, lA[i]);
#pragma unroll
    for (int i = 0; i < 4; i++) gll16(gB[i] + k0, lB[i]);
    __syncthreads();
#pragma unroll
    for (int s = 0; s < 2; s++) {
      const int pofs = ((s * 4 + quad) ^ (l15 & 7)) << 3;
      bf16x8 av[4], bv[4];
#pragma unroll
      for (int i = 0; i < 4; i++)
        av[i] = *(const bf16x8*)&As[(wr + i * 16 + l15) * 64 + pofs];
#pragma unroll
      for (int j = 0; j < 4; j++)
        bv[j] = *(const bf16x8*)&Bs[(wc + j * 16 + l15) * 64 + pofs];
#pragma unroll
      for (int i = 0; i < 4; i++)
#pragma unroll
        for (int j = 0; j < 4; j++)
          acc[i][j] = __builtin_amdgcn_mfma_f32_16x16x32_bf16(av[i], bv[j], acc[i][j], 0, 0, 0);
    }
    __syncthreads();
  }
#pragma unroll
  for (int j = 0; j < 4; j++) {
    int col = n0 + wc + j * 16 + l15;
    float bb = bias[col];
#pragma unroll
    for (int i = 0; i < 4; i++)
#pragma unroll
      for (int r = 0; r < 4; r++) {
        int m = m0 + wr + i * 16 + quad * 4 + r;  // C/D layout (m89/m91)
        out[(size_t)m * DIM + col] = (bf16_t)(acc[i][j][r] + bb);
      }
  }
}

// ---------------- MFMA gating: logits -> argmax+softmax inline -------------
// act [T,1024] bf16; WgP [128][8][8] bf16 (B-frag layout). M=64 per block.
__global__ __launch_bounds__(256) void k_gate_mm(
    const bf16_t* __restrict__ act, const bf16_t* __restrict__ WgP,
    int* __restrict__ idx, float* __restrict__ gate) {
  __shared__ alignas(16) bf16_t As[64 * 64];    // 8 KB
  __shared__ alignas(16) bf16_t WgS[128 * 64];  // 16 KB  [kc][8][8]
  __shared__ float L[64][8];
  const int tid = threadIdx.x;
  const int lane = tid & 63, wave = tid >> 6;
  const int quad = lane >> 4, l15 = lane & 15;
  const int m0 = blockIdx.x * 64;
  const int kc = (tid & 7) ^ ((tid >> 3) & 7);
  const int rbase = tid >> 3;  // 0..31

  // stage WgS once. NOTE: global address must be PER-LANE (m104/m108) —
  // global_load_lds writes LDS at uniform base + lane*16 from each lane's
  // own global pointer. (Round-4 bug: uniform global addr -> replicated
  // chunks -> identical expert columns -> all tokens routed to expert 0.)
#pragma unroll
  for (int j = 0; j < 4; j++)
    gll16(WgP + (j * 256 + wave * 64 + lane) * 8,
          &WgS[(j * 256 + wave * 64) * 8]);

  const bf16_t* gA[2];
  bf16_t* lA[2];
#pragma unroll
  for (int i = 0; i < 2; i++) {
    gA[i] = act + (size_t)(m0 + rbase + 32 * i) * DIM + kc * 8;
    lA[i] = &As[wave * 512 + i * 2048];
  }

  fx4 acc = (fx4)0.0f;
  for (int k0 = 0; k0 < DIM; k0 += 64) {
#pragma unroll
    for (int i = 0; i < 2; i++) gll16(gA[i] + k0, lA[i]);
    __syncthreads();
#pragma unroll
    for (int s = 0; s < 2; s++) {
      const int pofs = ((s * 4 + quad) ^ (l15 & 7)) << 3;
      bf16x8 av = *(const bf16x8*)&As[(wave * 16 + l15) * 64 + pofs];
      // B-frag: element jj = Wg[k0+s*32+quad*8+jj][e=l15&7]; cols 8..15 dup
      bf16x8 bv = *(const bf16x8*)&WgS[((k0 >> 3) + s * 4 + quad) * 64 + (l15 & 7) * 8];
      acc = __builtin_amdgcn_mfma_f32_16x16x32_bf16(av, bv, acc, 0, 0, 0);
    }
    __syncthreads();
  }
  if (l15 < 8) {
#pragma unroll
    for (int r = 0; r < 4; r++) L[wave * 16 + quad * 4 + r][l15] = acc[r];
  }
  __syncthreads();
  if (tid < 64) {
    float lg[8];
#pragma unroll
    for (int e = 0; e < 8; e++) lg[e] = L[tid][e];
    float best = lg[0];
    int bi = 0;
#pragma unroll
    for (int e = 1; e < 8; e++)
      if (lg[e] > best) { best = lg[e]; bi = e; }  // strict >: first max wins
    float s = 0.f;
#pragma unroll
    for (int e = 0; e < 8; e++) s += expf(lg[e] - best);
    idx[m0 + tid] = bi;
    gate[m0 + tid] = 1.0f / s;
  }
}

// ---------------- routing: block e builds tok list for expert e ------------
__global__ __launch_bounds__(1024) void k_route(
    const int* __restrict__ idx, int* __restrict__ tok, int* __restrict__ cnt,
    int* __restrict__ drop, int* __restrict__ ndrop) {
  const int e = blockIdx.x;
  const int tid = threadIdx.x, lane = tid & 63, wv = tid >> 6;
  __shared__ int wsum[16];
  const int4* p = (const int4*)(idx + tid * 16);
  int m[16];
  int c = 0;
#pragma unroll
  for (int j = 0; j < 4; j++) {
    int4 v = p[j];
    m[j * 4 + 0] = (v.x == e);
    m[j * 4 + 1] = (v.y == e);
    m[j * 4 + 2] = (v.z == e);
    m[j * 4 + 3] = (v.w == e);
    c += m[j * 4] + m[j * 4 + 1] + m[j * 4 + 2] + m[j * 4 + 3];
  }
  int sc = c;  // intra-wave inclusive scan
#pragma unroll
  for (int off = 1; off < 64; off <<= 1) {
    int n = __shfl_up(sc, off);
    if (lane >= off) sc += n;
  }
  if (lane == 63) wsum[wv] = sc;
  __syncthreads();
  int wb = 0, tot = 0;
#pragma unroll
  for (int i = 0; i < 16; i++) {
    int s = wsum[i];
    tot += s;
    if (i < wv) wb += s;
  }
  int pos = wb + sc - c;  // exclusive prefix for this thread
#pragma unroll
  for (int j = 0; j < 16; j++) {
    if (m[j]) {
      if (pos < CAP) {
        tok[e * CAP + pos] = tid * 16 + j;
      } else {
        int di = atomicAdd(ndrop, 1);
        drop[di] = tid * 16 + j;
      }
      pos++;
    }
  }
  if (tid == 0) cnt[e] = tot < CAP ? tot : CAP;
}

// ---------------- zero rows of dropped tokens ------------------------------
__global__ __launch_bounds__(128) void k_zero_rows(
    bf16_t* __restrict__ buf, const int* __restrict__ drop,
    const int* __restrict__ ndrop) {
  const int nd = *ndrop;
  const uint4 z = {0u, 0u, 0u, 0u};
  for (int j = blockIdx.x; j < nd; j += gridDim.x) {
    int t = drop[j];
    ((uint4*)(buf + (size_t)t * DIM))[threadIdx.x] = z;
  }
}

// ---------------- expert GEMM with gathered A + combine epilogue -----------
__global__ __launch_bounds__(256) void k_gemm_expert(
    const bf16_t* __restrict__ Ain, const bf16_t* __restrict__ Wt,
    const float* __restrict__ be, const int* __restrict__ tok,
    const int* __restrict__ cnt, const float* __restrict__ gate,
    const bf16_t* __restrict__ zp, bf16_t* __restrict__ outp) {
  // XCD-aware decode: id&7 = expert = XCD slot -> expert weights (2 MB)
  // stay resident in that XCD's L2 across all 16 c-blocks.
  const int id = blockIdx.x;
  const int e = id & 7;
  const int j_ = id >> 3;
  const int c0 = (j_ >> 3) * 128;
  const int n0 = (j_ & 7) * 128;
  const int count = cnt[e];
  if (c0 >= count) return;
  const bf16_t* Bt = Wt + (size_t)e * DIM * DIM;
  const float* bias = be + (size_t)e * DIM;
  const int* tk = tok + e * CAP;

  __shared__ alignas(16) bf16_t As[128 * 64];
  __shared__ alignas(16) bf16_t Bs[128 * 64];
  const int tid = threadIdx.x;
  const int lane = tid & 63, wave = tid >> 6;
  const int quad = lane >> 4, l15 = lane & 15;
  const int wr = (wave >> 1) * 64, wc = (wave & 1) * 64;
  const int kc = (tid & 7) ^ ((tid >> 3) & 7);
  const int rbase = tid >> 3;

  const bf16_t* gA[4];
  const bf16_t* gB[4];
  bf16_t* lA[4];
  bf16_t* lB[4];
#pragma unroll
  for (int i = 0; i < 4; i++) {
    int r = rbase + 32 * i;
    int ca = c0 + r;
    gA[i] = (ca < count) ? Ain + (size_t)tk[ca] * DIM + kc * 8 : zp;
    gB[i] = Bt + (size_t)(n0 + r) * DIM + kc * 8;
    lA[i] = &As[(wave * 64 + 256 * i) * 8];
    lB[i] = &Bs[(wave * 64 + 256 * i) * 8];
  }

  fx4 acc[4][4];
#pragma unroll
  for (int i = 0; i < 4; i++)
#pragma unroll
    for (int j = 0; j < 4; j++) acc[i][j] = (fx4)0.0f;

  for (int k0 = 0; k0 < DIM; k0 += 64) {
#pragma unroll
    for (int i = 0; i < 4; i++) gll16(gA[i] + k0, lA[i]);
#pragma unroll
    for (int i = 0; i < 4; i++) gll16(gB[i] + k0, lB[i]);
    __syncthreads();
#pragma unroll
    for (int s = 0; s < 2; s++) {
      const int pofs = ((s * 4 + quad) ^ (l15 & 7)) << 3;
      bf16x8 av[4], bv[4];
#pragma unroll
      for (int i = 0; i < 4; i++)
        av[i] = *(const bf16x8*)&As[(wr + i * 16 + l15) * 64 + pofs];
#pragma unroll
      for (int j = 0; j < 4; j++)
        bv[j] = *(const bf16x8*)&Bs[(wc + j * 16 + l15) * 64 + pofs];
#pragma unroll
      for (int i = 0; i < 4; i++)
#pragma unroll
        for (int j = 0; j < 4; j++)
          acc[i][j] = __builtin_amdgcn_mfma_f32_16x16x32_bf16(av[i], bv[j], acc[i][j], 0, 0, 0);
    }
    __syncthreads();
  }
  // combine: out[t] = gate[t] * (acc + be[e]); dropped rows zeroed separately
#pragma unroll
  for (int i = 0; i < 4; i++)
#pragma unroll
    for (int r = 0; r < 4; r++) {
      int c = c0 + wr + i * 16 + quad * 4 + r;
      if (c < count) {
        int t = tk[c];
        float g = gate[t];
#pragma unroll
        for (int j = 0; j < 4; j++) {
          int col = n0 + wc + j * 16 + l15;
          outp[(size_t)t * DIM + col] = (bf16_t)((acc[i][j][r] + bias[col]) * g);
        }
      }
    }
}

// ---------------- residual mean over S (vectorized, atomics) ---------------
__global__ __launch_bounds__(256) void k_reduce_sent(
    const bf16_t* __restrict__ h, const bf16_t* __restrict__ o2,
    float* __restrict__ sent) {
  const int tid = threadIdx.x;
  const int d8 = (tid & 127) * 8;
  const int sg = tid >> 7;  // 0/1
  const int b = blockIdx.y;
  const int s0 = blockIdx.x * 64 + sg * 32;
  float acc[8] = {0.f, 0.f, 0.f, 0.f, 0.f, 0.f, 0.f, 0.f};
  const size_t base = ((size_t)b * SEQ + s0) * DIM + d8;
  for (int i = 0; i < 32; i++) {
    union { bf16_t v[8]; uint4 u; } hh, oo;
    hh.u = *(const uint4*)&h[base + (size_t)i * DIM];
    oo.u = *(const uint4*)&o2[base + (size_t)i * DIM];
#pragma unroll
    for (int j = 0; j < 8; j++) acc[j] += (float)hh.v[j] + (float)oo.v[j];
  }
#pragma unroll
  for (int j = 0; j < 8; j++)
    atomicAdd(&sent[b * DIM + d8 + j], acc[j] * (1.0f / SEQ));
}

// ---------------- loss: one block per batch, atomicAdd into out ------------
__global__ __launch_bounds__(256) void k_loss(
    const float* __restrict__ sent, const int* __restrict__ y,
    float* __restrict__ out) {
  const int b = blockIdx.x, tid = threadIdx.x;
  const float* sb = sent + b * DIM;
  __shared__ float red[256];
  float m = -1e30f;
  for (int d = tid; d < DIM; d += 256) m = fmaxf(m, sb[d]);
  red[tid] = m;
  __syncthreads();
  for (int s = 128; s; s >>= 1) {
    if (tid < s) red[tid] = fmaxf(red[tid], red[tid + s]);
    __syncthreads();
  }
  m = red[0];
  __syncthreads();
  float sum = 0.f;
  for (int d = tid; d < DIM; d += 256) sum += expf(sb[d] - m);
  red[tid] = sum;
  __syncthreads();
  for (int s = 128; s; s >>= 1) {
    if (tid < s) red[tid] += red[tid + s];
    __syncthreads();
  }
  if (tid == 0) atomicAdd(out, (m + logf(red[0]) - sb[y[b]]) * (1.0f / BATCH));
}

// ---------------------------------------------------------------------------
extern "C" void kernel_launch(void* const* d_in, const int* in_sizes, int n_in,
                              void* d_out, int out_size, void* d_ws, size_t ws_size,
                              hipStream_t stream) {
  (void)in_sizes; (void)n_in; (void)out_size; (void)ws_size;
  const float* x   = (const float*)d_in[0];
  const int*   y   = (const int*)d_in[1];
  const float* W1  = (const float*)d_in[2];
  const float* b1  = (const float*)d_in[3];
  const float* Wg2 = (const float*)d_in[4];
  const float* We2 = (const float*)d_in[5];
  const float* be2 = (const float*)d_in[6];
  const float* Wg3 = (const float*)d_in[7];
  const float* We3 = (const float*)d_in[8];
  const float* be3 = (const float*)d_in[9];

  char* p = (char*)d_ws;
  size_t off = 0;
  auto carve = [&](size_t bytes) -> char* {
    char* r = p + off;
    off += (bytes + 255) & ~(size_t)255;
    return r;
  };
  bf16_t* Wt   = (bf16_t*)carve((size_t)17 * DIM * DIM * 2);  // 0:W1t 1..8:We2t 9..16:We3t
  bf16_t* WgP  = (bf16_t*)carve(2 * 128 * 8 * 8 * 2);         // gate B-frag packs
  bf16_t* h    = (bf16_t*)carve((size_t)TOKS * DIM * 2);
  bf16_t* o1   = (bf16_t*)carve((size_t)TOKS * DIM * 2);
  bf16_t* o2   = (bf16_t*)carve((size_t)TOKS * DIM * 2);  // aliases xb lifetime
  int*    idx  = (int*)carve(TOKS * 4);
  float*  gate = (float*)carve(TOKS * 4);
  int*    tok  = (int*)carve(NEXP * CAP * 4);
  int*    cnt  = (int*)carve(NEXP * 4);
  int*    drop2 = (int*)carve(TOKS * 4);
  int*    drop3 = (int*)carve(TOKS * 4);
  // --- contiguous zero region: sent, zp, ndrop2, ndrop3 (single memset) ---
  size_t zoff0 = off;
  float*  sent = (float*)carve(BATCH * DIM * 4);
  bf16_t* zp   = (bf16_t*)carve(4096);
  int*    nd2  = (int*)carve(256);
  int*    nd3  = (int*)carve(256);
  size_t zbytes = off - zoff0;
  bf16_t* xb   = o2;  // x-bf16 dead before o2 is born

  hipMemsetAsync(sent, 0, zbytes, stream);  // sent + zp + nd2 + nd3
  hipMemsetAsync(d_out, 0, 4, stream);      // loss accumulates via atomics

  // prep: weight transpose+convert, gate weight pack, x convert
  k_prep_w<<<dim3(16, 16, 17), 256, 0, stream>>>(W1, We2, We3, Wt);
  k_prep_wg<<<2, 256, 0, stream>>>(Wg2, Wg3, WgP);
  k_cvt_x<<<TOKS * DIM / 8 / 256, 256, 0, stream>>>(x, xb);

  // dense pre-layer
  k_gemm_dense<<<(TOKS / 128) * (DIM / 128), 256, 0, stream>>>(xb, Wt, b1, h);

  // MoE layer 2
  k_gate_mm<<<TOKS / 64, 256, 0, stream>>>(h, WgP, idx, gate);
  k_route<<<NEXP, 1024, 0, stream>>>(idx, tok, cnt, drop2, nd2);
  k_zero_rows<<<256, 128, 0, stream>>>(o1, drop2, nd2);
  k_gemm_expert<<<NEXP * (CAP / 128) * (DIM / 128), 256, 0, stream>>>(
      h, Wt + (size_t)1 * DIM * DIM, be2, tok, cnt, gate, zp, o1);

  // MoE layer 3
  k_gate_mm<<<TOKS / 64, 256, 0, stream>>>(o1, WgP + 128 * 8 * 8, idx, gate);
  k_route<<<NEXP, 1024, 0, stream>>>(idx, tok, cnt, drop3, nd3);
  k_zero_rows<<<256, 128, 0, stream>>>(o2, drop3, nd3);
  k_gemm_expert<<<NEXP * (CAP / 128) * (DIM / 128), 256, 0, stream>>>(
      o1, Wt + (size_t)9 * DIM * DIM, be3, tok, cnt, gate, zp, o2);

  // residual + sentence mean + CE loss
  k_reduce_sent<<<dim3(SEQ / 64, BATCH), 256, 0, stream>>>(h, o2, sent);
  k_loss<<<BATCH, 256, 0, stream>>>(sent, y, (float*)d_out);
}